// Round 1
// baseline (5452.613 us; speedup 1.0000x reference)
//
#include <hip/hip_runtime.h>

#define SQ 65536
#define BSEG 256
#define NSEG (SQ / BSEG)
#define NEGV (-10000.0f)

// ws layout (bytes):
//   [0, SQ*8)              backpointer bytes, group of 8 per step (6 used)
//   [SQ*8, +4)             terminal best tag (u32)
//   [SQ*8+32, +NSEG*8)     segment maps (6 bytes used per 8)
//   [.., +NSEG)            entry tags e[s]
#define BP_OFF 0u
#define BEST_OFF ((unsigned)SQ * 8u)
#define MAPS_OFF (BEST_OFF + 32u)
#define E_OFF (MAPS_OFF + (unsigned)NSEG * 8u)

__device__ __forceinline__ float rl(float v, int l) {
  return __int_as_float(__builtin_amdgcn_readlane(__float_as_int(v), l));
}

__global__ __launch_bounds__(64, 1)
void viterbi_fwd(const float* __restrict__ feats, const float* __restrict__ trans,
                 float* __restrict__ out, unsigned char* __restrict__ ws) {
  const int lane = threadIdx.x;
  const int nn = lane < 6 ? lane : 0;
  // transition row for this lane's "next" tag: trans[nn][p]
  const float T0 = trans[nn * 6 + 0], T1 = trans[nn * 6 + 1], T2 = trans[nn * 6 + 2],
              T3 = trans[nn * 6 + 3], T4 = trans[nn * 6 + 4], T5 = trans[nn * 6 + 5];
  // init forward_var: NEG everywhere except START(4)=0
  float fv0 = NEGV, fv1 = NEGV, fv2 = NEGV, fv3 = NEGV, fv4 = 0.0f, fv5 = NEGV;
  unsigned char* bpb = ws + BP_OFF;
  const float* fp = feats + nn;

  float fq[16];
#pragma unroll
  for (int i = 0; i < 16; ++i) fq[i] = fp[i * 6];

  auto step = [&](float ft, int tt) {
    // scores[n][p] = fv[p] + trans[n][p]  (exact reference fp order)
    float sc0 = fv0 + T0, sc1 = fv1 + T1, sc2 = fv2 + T2;
    float sc3 = fv3 + T3, sc4 = fv4 + T4, sc5 = fv5 + T5;
    float m012 = fmaxf(fmaxf(sc0, sc1), sc2);
    float m345 = fmaxf(fmaxf(sc3, sc4), sc5);
    float m = fmaxf(m012, m345);
    // first-index argmax (numpy tie rule)
    int i012 = (sc0 >= m012) ? 0 : ((sc1 >= m012) ? 1 : 2);
    int i345 = (sc3 >= m345) ? 3 : ((sc4 >= m345) ? 4 : 5);
    int idx = (m012 >= m) ? i012 : i345;
    if (lane < 6) bpb[(unsigned)tt * 8u + (unsigned)lane] = (unsigned char)idx;
    float nfv = m + ft;  // + feat, reference order
    fv0 = rl(nfv, 0); fv1 = rl(nfv, 1); fv2 = rl(nfv, 2);
    fv3 = rl(nfv, 3); fv4 = rl(nfv, 4); fv5 = rl(nfv, 5);
  };

  // main loop with 16-step register prefetch; last block peeled (no reload)
  for (int blk = 0; blk < SQ / 16 - 1; ++blk) {
    const int t = blk * 16;
#pragma unroll
    for (int i = 0; i < 16; ++i) {
      step(fq[i], t + i);
      fq[i] = fp[(t + i + 16) * 6];  // max index = 65535: in bounds
    }
  }
  {
    const int t = SQ - 16;
#pragma unroll
    for (int i = 0; i < 16; ++i) step(fq[i], t + i);
  }

  // terminal = fv + transitions[STOP]; argmax first-max; score = max
  const float q0 = trans[5 * 6 + 0], q1 = trans[5 * 6 + 1], q2 = trans[5 * 6 + 2],
              q3 = trans[5 * 6 + 3], q4 = trans[5 * 6 + 4], q5 = trans[5 * 6 + 5];
  float tv0 = fv0 + q0, tv1 = fv1 + q1, tv2 = fv2 + q2;
  float tv3 = fv3 + q3, tv4 = fv4 + q4, tv5 = fv5 + q5;
  float bm = tv0; int bi = 0;
  if (tv1 > bm) { bm = tv1; bi = 1; }
  if (tv2 > bm) { bm = tv2; bi = 2; }
  if (tv3 > bm) { bm = tv3; bi = 3; }
  if (tv4 > bm) { bm = tv4; bi = 4; }
  if (tv5 > bm) { bm = tv5; bi = 5; }
  if (lane == 0) {
    out[0] = bm;
    *(unsigned*)(ws + BEST_OFF) = (unsigned)bi;
  }
}

// Phase 1: per-segment composed backpointer map via 6 lane-hypotheses.
// Segment s applies bp[j] for j = hi..lo (lo = s*BSEG+1,
// hi = (s+1)*BSEG, except last segment hi = SQ-1).
__global__ __launch_bounds__(64, 1)
void bt_maps(unsigned char* __restrict__ ws) {
  const int s = blockIdx.x;
  const int lane = threadIdx.x;
  int x = lane < 6 ? lane : 5;
  const unsigned long long* g = (const unsigned long long*)(ws + BP_OFF);
  const int lo = s * BSEG + 1;
  const int hi = (s == NSEG - 1) ? (SQ - 1) : (s + 1) * BSEG;
#pragma unroll 8
  for (int j = hi; j >= lo; --j) {
    unsigned long long w = g[j];            // uniform address, independent loads
    x = (int)((w >> (x * 8)) & 7ull);       // dependent select only
  }
  if (lane < 6) ws[MAPS_OFF + (unsigned)s * 8u + (unsigned)lane] = (unsigned char)x;
}

// Phase 2: sequential chain over segment maps -> entry tag e[s] = path[s*BSEG].
__global__ __launch_bounds__(64, 1)
void bt_chain(unsigned char* __restrict__ ws) {
  __shared__ unsigned char ml[NSEG * 8];
  const unsigned* src = (const unsigned*)(ws + MAPS_OFF);
  unsigned* dstw = (unsigned*)ml;
  for (int i = threadIdx.x; i < NSEG * 2; i += 64) dstw[i] = src[i];
  __syncthreads();
  if (threadIdx.x == 0) {
    int x = (int)*(const unsigned*)(ws + BEST_OFF);
    for (int s = NSEG - 1; s >= 1; --s) {
      x = ml[s * 8 + x];                    // e[s] = M_s[e[s+1]]
      ws[E_OFF + (unsigned)s] = (unsigned char)x;
    }
  }
}

// Phase 3: parallel exact path emission. out[1+t] = path[t].
__global__ __launch_bounds__(64, 1)
void bt_emit(const unsigned char* __restrict__ ws, float* __restrict__ out) {
  const int s = blockIdx.x;
  if (threadIdx.x != 0) return;
  const unsigned long long* g = (const unsigned long long*)(ws + BP_OFF);
  int x, hi;
  const int lo = s * BSEG + 1;
  if (s == NSEG - 1) {
    x = (int)*(const unsigned*)(ws + BEST_OFF);
    out[1 + (SQ - 1)] = (float)x;           // path[S-1] = best
    hi = SQ - 1;
  } else {
    x = ws[E_OFF + (unsigned)(s + 1)];      // path[(s+1)*BSEG]
    hi = (s + 1) * BSEG;
  }
#pragma unroll 8
  for (int j = hi; j >= lo; --j) {
    unsigned long long w = g[j];
    x = (int)((w >> (x * 8)) & 7ull);       // path[j-1] = bp[j][path[j]]
    out[j] = (float)x;                      // out[1+(j-1)]
  }
}

extern "C" void kernel_launch(void* const* d_in, const int* in_sizes, int n_in,
                              void* d_out, int out_size, void* d_ws, size_t ws_size,
                              hipStream_t stream) {
  const float* feats = (const float*)d_in[0];
  const float* trans = (const float*)d_in[1];
  float* out = (float*)d_out;
  unsigned char* ws = (unsigned char*)d_ws;

  viterbi_fwd<<<1, 64, 0, stream>>>(feats, trans, out, ws);
  bt_maps<<<NSEG, 64, 0, stream>>>(ws);
  bt_chain<<<1, 64, 0, stream>>>(ws);
  bt_emit<<<NSEG, 64, 0, stream>>>(ws, out);
}

// Round 2
// 4620.476 us; speedup vs baseline: 1.1801x; 1.1801x over previous
//
#include <hip/hip_runtime.h>

#define SQ 65536
#define BSEG 256
#define NSEG (SQ / BSEG)
#define NEGV (-10000.0f)

// ws layout (bytes):
//   [0, SQ*8)              backpointer bytes, group of 8 per step (6 used)
//   [SQ*8, +4)             terminal best tag (u32)
//   [SQ*8+32, +NSEG*8)     segment maps (6 bytes used per 8)
//   [.., +NSEG)            entry tags e[s]
#define BP_OFF 0u
#define BEST_OFF ((unsigned)SQ * 8u)
#define MAPS_OFF (BEST_OFF + 32u)
#define E_OFF (MAPS_OFF + (unsigned)NSEG * 8u)

__device__ __forceinline__ float rl(float v, int l) {
  return __int_as_float(__builtin_amdgcn_readlane(__float_as_int(v), l));
}

__global__ __launch_bounds__(64, 1)
void viterbi_fwd(const float* __restrict__ feats, const float* __restrict__ trans,
                 float* __restrict__ out, unsigned char* __restrict__ ws) {
  const int lane = threadIdx.x;
  if (lane >= 6) return;  // exec mask set ONCE; no per-step divergence below
  // transition row for this lane's "next" tag: trans[lane][p]
  const float T0 = trans[lane * 6 + 0], T1 = trans[lane * 6 + 1], T2 = trans[lane * 6 + 2],
              T3 = trans[lane * 6 + 3], T4 = trans[lane * 6 + 4], T5 = trans[lane * 6 + 5];
  // init forward_var: NEG everywhere except START(4)=0
  float fv0 = NEGV, fv1 = NEGV, fv2 = NEGV, fv3 = NEGV, fv4 = 0.0f, fv5 = NEGV;
  unsigned char* bpb = ws + BP_OFF + lane;
  const float* fp = feats + lane;

  float fq[16];
#pragma unroll
  for (int i = 0; i < 16; ++i) fq[i] = fp[i * 6];

  auto step = [&](float ft, int tt) {
    // scores[n][p] = fv[p] + trans[n][p]  (exact reference fp add order)
    float sc0 = fv0 + T0, sc1 = fv1 + T1, sc2 = fv2 + T2;
    float sc3 = fv3 + T3, sc4 = fv4 + T4, sc5 = fv5 + T5;
    // max tree: re-association is exact (max has no rounding); fmaxf(fmaxf(a,b),c) -> v_max3_f32
    float m = fmaxf(fmaxf(fmaxf(sc0, sc1), sc2), fmaxf(fmaxf(sc3, sc4), sc5));
    // first-index argmax (numpy tie rule): smallest i with sc_i == m
    int idx = 5;
    idx = (sc4 >= m) ? 4 : idx;
    idx = (sc3 >= m) ? 3 : idx;
    idx = (sc2 >= m) ? 2 : idx;
    idx = (sc1 >= m) ? 1 : idx;
    idx = (sc0 >= m) ? 0 : idx;
    bpb[(unsigned)tt * 8u] = (unsigned char)idx;  // branch-free: only 6 lanes live
    float nfv = m + ft;  // + feat, reference order
    fv0 = rl(nfv, 0); fv1 = rl(nfv, 1); fv2 = rl(nfv, 2);
    fv3 = rl(nfv, 3); fv4 = rl(nfv, 4); fv5 = rl(nfv, 5);
  };

  // main loop with 16-step register prefetch; last block peeled (no reload)
  for (int blk = 0; blk < SQ / 16 - 1; ++blk) {
    const int t = blk * 16;
#pragma unroll
    for (int i = 0; i < 16; ++i) {
      step(fq[i], t + i);
      fq[i] = fp[(t + i + 16) * 6];  // max index = 65535: in bounds
    }
  }
  {
    const int t = SQ - 16;
#pragma unroll
    for (int i = 0; i < 16; ++i) step(fq[i], t + i);
  }

  // terminal = fv + transitions[STOP]; argmax first-max; score = max
  const float q0 = trans[5 * 6 + 0], q1 = trans[5 * 6 + 1], q2 = trans[5 * 6 + 2],
              q3 = trans[5 * 6 + 3], q4 = trans[5 * 6 + 4], q5 = trans[5 * 6 + 5];
  float tv0 = fv0 + q0, tv1 = fv1 + q1, tv2 = fv2 + q2;
  float tv3 = fv3 + q3, tv4 = fv4 + q4, tv5 = fv5 + q5;
  float bm = tv0; int bi = 0;
  if (tv1 > bm) { bm = tv1; bi = 1; }
  if (tv2 > bm) { bm = tv2; bi = 2; }
  if (tv3 > bm) { bm = tv3; bi = 3; }
  if (tv4 > bm) { bm = tv4; bi = 4; }
  if (tv5 > bm) { bm = tv5; bi = 5; }
  if (lane == 0) {
    out[0] = bm;
    *(unsigned*)(ws + BEST_OFF) = (unsigned)bi;
  }
}

// Phase 1: per-segment composed backpointer map via 6 lane-hypotheses.
__global__ __launch_bounds__(64, 1)
void bt_maps(unsigned char* __restrict__ ws) {
  const int s = blockIdx.x;
  const int lane = threadIdx.x;
  int x = lane < 6 ? lane : 5;
  const unsigned long long* g = (const unsigned long long*)(ws + BP_OFF);
  const int lo = s * BSEG + 1;
  const int hi = (s == NSEG - 1) ? (SQ - 1) : (s + 1) * BSEG;
#pragma unroll 8
  for (int j = hi; j >= lo; --j) {
    unsigned long long w = g[j];            // uniform address, independent loads
    x = (int)((w >> (x * 8)) & 7ull);       // dependent select only
  }
  if (lane < 6) ws[MAPS_OFF + (unsigned)s * 8u + (unsigned)lane] = (unsigned char)x;
}

// Phase 2: sequential chain over segment maps -> entry tag e[s] = path[s*BSEG].
__global__ __launch_bounds__(64, 1)
void bt_chain(unsigned char* __restrict__ ws) {
  __shared__ unsigned char ml[NSEG * 8];
  const unsigned* src = (const unsigned*)(ws + MAPS_OFF);
  unsigned* dstw = (unsigned*)ml;
  for (int i = threadIdx.x; i < NSEG * 2; i += 64) dstw[i] = src[i];
  __syncthreads();
  if (threadIdx.x == 0) {
    int x = (int)*(const unsigned*)(ws + BEST_OFF);
    for (int s = NSEG - 1; s >= 1; --s) {
      x = ml[s * 8 + x];                    // e[s] = M_s[e[s+1]]
      ws[E_OFF + (unsigned)s] = (unsigned char)x;
    }
  }
}

// Phase 3: parallel exact path emission. out[1+t] = path[t].
__global__ __launch_bounds__(64, 1)
void bt_emit(const unsigned char* __restrict__ ws, float* __restrict__ out) {
  const int s = blockIdx.x;
  if (threadIdx.x != 0) return;
  const unsigned long long* g = (const unsigned long long*)(ws + BP_OFF);
  int x, hi;
  const int lo = s * BSEG + 1;
  if (s == NSEG - 1) {
    x = (int)*(const unsigned*)(ws + BEST_OFF);
    out[1 + (SQ - 1)] = (float)x;           // path[S-1] = best
    hi = SQ - 1;
  } else {
    x = ws[E_OFF + (unsigned)(s + 1)];      // path[(s+1)*BSEG]
    hi = (s + 1) * BSEG;
  }
#pragma unroll 8
  for (int j = hi; j >= lo; --j) {
    unsigned long long w = g[j];
    x = (int)((w >> (x * 8)) & 7ull);       // path[j-1] = bp[j][path[j]]
    out[j] = (float)x;                      // out[1+(j-1)]
  }
}

extern "C" void kernel_launch(void* const* d_in, const int* in_sizes, int n_in,
                              void* d_out, int out_size, void* d_ws, size_t ws_size,
                              hipStream_t stream) {
  const float* feats = (const float*)d_in[0];
  const float* trans = (const float*)d_in[1];
  float* out = (float*)d_out;
  unsigned char* ws = (unsigned char*)d_ws;

  viterbi_fwd<<<1, 64, 0, stream>>>(feats, trans, out, ws);
  bt_maps<<<NSEG, 64, 0, stream>>>(ws);
  bt_chain<<<1, 64, 0, stream>>>(ws);
  bt_emit<<<NSEG, 64, 0, stream>>>(ws, out);
}

// Round 3
// 2359.589 us; speedup vs baseline: 2.3108x; 1.9582x over previous
//
#include <hip/hip_runtime.h>

#define SQ 65536
#define BSEG 256
#define NSEG (SQ / BSEG)
#define NEGV (-10000.0f)
#define PADV (-1.0e30f)

// ---- New (deferred-argmax) ws layout ----
#define TRACE_OFF 0u                          // SQ*32 B: fv trace, 8 floats/step (6 used)
#define BP_OFF    ((unsigned)SQ * 32u)        // SQ*8 B: packed bp bytes
#define BEST_OFF  (BP_OFF + (unsigned)SQ * 8u)
#define MAPS_OFF  (BEST_OFF + 32u)
#define E_OFF     (MAPS_OFF + (unsigned)NSEG * 8u)
#define WS_NEEDED ((size_t)(E_OFF + NSEG + 64))

// ---- Old (fallback) ws layout ----
#define OBP_OFF   0u
#define OBEST_OFF ((unsigned)SQ * 8u)
#define OMAPS_OFF (OBEST_OFF + 32u)
#define OE_OFF    (OMAPS_OFF + (unsigned)NSEG * 8u)

__device__ __forceinline__ float rl(float v, int l) {
  return __int_as_float(__builtin_amdgcn_readlane(__float_as_int(v), l));
}

template <int K>
__device__ __forceinline__ float ror16(float v) {
  return __int_as_float(
      __builtin_amdgcn_update_dpp(0, __float_as_int(v), 0x120 + K, 0xF, 0xF, true));
}
template <int K>
__device__ __forceinline__ int ror16i(int v) {
  return __builtin_amdgcn_update_dpp(0, v, 0x120 + K, 0xF, 0xF, true);
}

// ================== NEW forward: DPP distribution, deferred argmax ==================
__global__ __launch_bounds__(64, 1)
void viterbi_fwd_dpp(const float* __restrict__ feats, const float* __restrict__ trans,
                     unsigned char* __restrict__ ws) {
  const int lane = threadIdx.x & 63;
  const int r = lane & 7;
  const int row = r < 6 ? r : 5;  // lanes 6,7 are exact replicas of tag 5

  // Probe DPP row_ror direction (HW convention safe): lane0 receives 1 -> dir=+1 else -1
  int w = ror16i<1>(lane & 15);
  const int dir = (__builtin_amdgcn_readfirstlane(w) == 1) ? 1 : -1;

  // TT[k] pairs with the value arriving via ror16<k>: that value is fv of tag (r + dir*k) & 7
  float TT[8];
#pragma unroll
  for (int k = 0; k < 8; ++k) {
    int p = (r + dir * k) & 7;
    TT[k] = (p < 6) ? trans[row * 6 + p] : PADV;
  }

  const float* fp = feats + row;                     // feat for this lane's tag
  float* tp = (float*)(ws + TRACE_OFF) + r;          // trace slot for this lane
  float nfv = (row == 4) ? 0.0f : NEGV;              // init fv (START=4 is 0)

  float fq[16];
#pragma unroll
  for (int i = 0; i < 16; ++i) fq[i] = fp[i * 6];

  auto step = [&](float ft, float* sp) {
    float d1 = ror16<1>(nfv), d2 = ror16<2>(nfv), d3 = ror16<3>(nfv), d4 = ror16<4>(nfv),
          d5 = ror16<5>(nfv), d6 = ror16<6>(nfv), d7 = ror16<7>(nfv);
    float s0 = nfv + TT[0], s1 = d1 + TT[1], s2 = d2 + TT[2], s3 = d3 + TT[3],
          s4 = d4 + TT[4], s5 = d5 + TT[5], s6 = d6 + TT[6], s7 = d7 + TT[7];
    float A = fmaxf(fmaxf(s0, s1), s2);   // v_max3
    float B = fmaxf(fmaxf(s3, s4), s5);   // v_max3
    float C = fmaxf(s6, s7);
    float M = fmaxf(fmaxf(A, B), C);      // v_max3 (max reassociation is exact)
    nfv = M + ft;                         // reference add order: max + feat
    *sp = nfv;                            // trace fv_{t+1}
  };

  for (int blk = 0; blk < SQ / 16 - 1; ++blk) {
    const int t = blk * 16;
#pragma unroll
    for (int i = 0; i < 16; ++i) {
      step(fq[i], tp + (t + i) * 8);
      fq[i] = fp[(t + i + 16) * 6];
    }
  }
  {
    const int t = SQ - 16;
#pragma unroll
    for (int i = 0; i < 16; ++i) step(fq[i], tp + (t + i) * 8);
  }
}

// ================== Parallel backpointer extraction (bit-exact recompute) ==================
__global__ __launch_bounds__(256)
void bp_kernel(const float* __restrict__ trans, unsigned char* __restrict__ ws) {
  const int t = blockIdx.x * 256 + threadIdx.x;
  float fv0, fv1, fv2, fv3, fv4, fv5;
  if (t == 0) {
    fv0 = NEGV; fv1 = NEGV; fv2 = NEGV; fv3 = NEGV; fv4 = 0.0f; fv5 = NEGV;
  } else {
    const float* f = (const float*)(ws + TRACE_OFF) + (unsigned)(t - 1) * 8u;
    fv0 = f[0]; fv1 = f[1]; fv2 = f[2]; fv3 = f[3]; fv4 = f[4]; fv5 = f[5];
  }
  unsigned long long acc = 0;
#pragma unroll
  for (int n = 0; n < 6; ++n) {
    float s0 = fv0 + trans[n * 6 + 0];
    float s1 = fv1 + trans[n * 6 + 1];
    float s2 = fv2 + trans[n * 6 + 2];
    float s3 = fv3 + trans[n * 6 + 3];
    float s4 = fv4 + trans[n * 6 + 4];
    float s5 = fv5 + trans[n * 6 + 5];
    float m = fmaxf(fmaxf(fmaxf(s0, s1), s2), fmaxf(fmaxf(s3, s4), s5));
    int idx = 5;
    idx = (s4 >= m) ? 4 : idx;
    idx = (s3 >= m) ? 3 : idx;
    idx = (s2 >= m) ? 2 : idx;
    idx = (s1 >= m) ? 1 : idx;
    idx = (s0 >= m) ? 0 : idx;  // numpy first-index tie rule
    acc |= (unsigned long long)idx << (8 * n);
  }
  ((unsigned long long*)(ws + BP_OFF))[t] = acc;
}

// ================== OLD forward (fallback if ws too small) ==================
__global__ __launch_bounds__(64, 1)
void viterbi_fwd_old(const float* __restrict__ feats, const float* __restrict__ trans,
                     float* __restrict__ out, unsigned char* __restrict__ ws) {
  const int lane = threadIdx.x;
  if (lane >= 6) return;
  const float T0 = trans[lane * 6 + 0], T1 = trans[lane * 6 + 1], T2 = trans[lane * 6 + 2],
              T3 = trans[lane * 6 + 3], T4 = trans[lane * 6 + 4], T5 = trans[lane * 6 + 5];
  float fv0 = NEGV, fv1 = NEGV, fv2 = NEGV, fv3 = NEGV, fv4 = 0.0f, fv5 = NEGV;
  unsigned char* bpb = ws + OBP_OFF + lane;
  const float* fp = feats + lane;
  float fq[16];
#pragma unroll
  for (int i = 0; i < 16; ++i) fq[i] = fp[i * 6];
  auto step = [&](float ft, int tt) {
    float sc0 = fv0 + T0, sc1 = fv1 + T1, sc2 = fv2 + T2;
    float sc3 = fv3 + T3, sc4 = fv4 + T4, sc5 = fv5 + T5;
    float m = fmaxf(fmaxf(fmaxf(sc0, sc1), sc2), fmaxf(fmaxf(sc3, sc4), sc5));
    int idx = 5;
    idx = (sc4 >= m) ? 4 : idx;
    idx = (sc3 >= m) ? 3 : idx;
    idx = (sc2 >= m) ? 2 : idx;
    idx = (sc1 >= m) ? 1 : idx;
    idx = (sc0 >= m) ? 0 : idx;
    bpb[(unsigned)tt * 8u] = (unsigned char)idx;
    float nfv = m + ft;
    fv0 = rl(nfv, 0); fv1 = rl(nfv, 1); fv2 = rl(nfv, 2);
    fv3 = rl(nfv, 3); fv4 = rl(nfv, 4); fv5 = rl(nfv, 5);
  };
  for (int blk = 0; blk < SQ / 16 - 1; ++blk) {
    const int t = blk * 16;
#pragma unroll
    for (int i = 0; i < 16; ++i) { step(fq[i], t + i); fq[i] = fp[(t + i + 16) * 6]; }
  }
  { const int t = SQ - 16;
#pragma unroll
    for (int i = 0; i < 16; ++i) step(fq[i], t + i); }
  const float q0 = trans[30], q1 = trans[31], q2 = trans[32],
              q3 = trans[33], q4 = trans[34], q5 = trans[35];
  float tv0 = fv0 + q0, tv1 = fv1 + q1, tv2 = fv2 + q2;
  float tv3 = fv3 + q3, tv4 = fv4 + q4, tv5 = fv5 + q5;
  float bm = tv0; int bi = 0;
  if (tv1 > bm) { bm = tv1; bi = 1; }
  if (tv2 > bm) { bm = tv2; bi = 2; }
  if (tv3 > bm) { bm = tv3; bi = 3; }
  if (tv4 > bm) { bm = tv4; bi = 4; }
  if (tv5 > bm) { bm = tv5; bi = 5; }
  if (lane == 0) { out[0] = bm; *(unsigned*)(ws + OBEST_OFF) = (unsigned)bi; }
}

// ================== Backtrack phases (offsets passed as args) ==================
__global__ __launch_bounds__(64, 1)
void bt_maps(unsigned char* __restrict__ ws, unsigned bp_off, unsigned maps_off) {
  const int s = blockIdx.x;
  const int lane = threadIdx.x;
  int x = lane < 6 ? lane : 5;
  const unsigned long long* g = (const unsigned long long*)(ws + bp_off);
  const int lo = s * BSEG + 1;
  const int hi = (s == NSEG - 1) ? (SQ - 1) : (s + 1) * BSEG;
#pragma unroll 8
  for (int j = hi; j >= lo; --j) {
    unsigned long long w = g[j];
    x = (int)((w >> (x * 8)) & 7ull);
  }
  if (lane < 6) ws[maps_off + (unsigned)s * 8u + (unsigned)lane] = (unsigned char)x;
}

// do_terminal!=0: compute terminal score/best from fv trace (new path) and write out[0].
__global__ __launch_bounds__(64, 1)
void bt_chain(const float* __restrict__ trans, float* __restrict__ out,
              unsigned char* __restrict__ ws, unsigned best_off, unsigned maps_off,
              unsigned e_off, int do_terminal) {
  __shared__ unsigned char ml[NSEG * 8];
  const unsigned* src = (const unsigned*)(ws + maps_off);
  unsigned* dstw = (unsigned*)ml;
  for (int i = threadIdx.x; i < NSEG * 2; i += 64) dstw[i] = src[i];
  __syncthreads();
  if (threadIdx.x == 0) {
    if (do_terminal) {
      const float* f = (const float*)(ws + TRACE_OFF) + (unsigned)(SQ - 1) * 8u;
      float bm = f[0] + trans[30]; int bi = 0;
      float tv;
      tv = f[1] + trans[31]; if (tv > bm) { bm = tv; bi = 1; }
      tv = f[2] + trans[32]; if (tv > bm) { bm = tv; bi = 2; }
      tv = f[3] + trans[33]; if (tv > bm) { bm = tv; bi = 3; }
      tv = f[4] + trans[34]; if (tv > bm) { bm = tv; bi = 4; }
      tv = f[5] + trans[35]; if (tv > bm) { bm = tv; bi = 5; }
      out[0] = bm;
      *(unsigned*)(ws + best_off) = (unsigned)bi;
    }
    int x = (int)*(const unsigned*)(ws + best_off);
    for (int s = NSEG - 1; s >= 1; --s) {
      x = ml[s * 8 + x];
      ws[e_off + (unsigned)s] = (unsigned char)x;
    }
  }
}

__global__ __launch_bounds__(64, 1)
void bt_emit(const unsigned char* __restrict__ ws, float* __restrict__ out,
             unsigned bp_off, unsigned best_off, unsigned e_off) {
  const int s = blockIdx.x;
  if (threadIdx.x != 0) return;
  const unsigned long long* g = (const unsigned long long*)(ws + bp_off);
  int x, hi;
  const int lo = s * BSEG + 1;
  if (s == NSEG - 1) {
    x = (int)*(const unsigned*)(ws + best_off);
    out[1 + (SQ - 1)] = (float)x;
    hi = SQ - 1;
  } else {
    x = ws[e_off + (unsigned)(s + 1)];
    hi = (s + 1) * BSEG;
  }
#pragma unroll 8
  for (int j = hi; j >= lo; --j) {
    unsigned long long w = g[j];
    x = (int)((w >> (x * 8)) & 7ull);
    out[j] = (float)x;
  }
}

extern "C" void kernel_launch(void* const* d_in, const int* in_sizes, int n_in,
                              void* d_out, int out_size, void* d_ws, size_t ws_size,
                              hipStream_t stream) {
  const float* feats = (const float*)d_in[0];
  const float* trans = (const float*)d_in[1];
  float* out = (float*)d_out;
  unsigned char* ws = (unsigned char*)d_ws;

  if (ws_size >= WS_NEEDED) {
    viterbi_fwd_dpp<<<1, 64, 0, stream>>>(feats, trans, ws);
    bp_kernel<<<NSEG, 256, 0, stream>>>(trans, ws);
    bt_maps<<<NSEG, 64, 0, stream>>>(ws, BP_OFF, MAPS_OFF);
    bt_chain<<<1, 64, 0, stream>>>(trans, out, ws, BEST_OFF, MAPS_OFF, E_OFF, 1);
    bt_emit<<<NSEG, 64, 0, stream>>>(ws, out, BP_OFF, BEST_OFF, E_OFF);
  } else {
    viterbi_fwd_old<<<1, 64, 0, stream>>>(feats, trans, out, ws);
    bt_maps<<<NSEG, 64, 0, stream>>>(ws, OBP_OFF, OMAPS_OFF);
    bt_chain<<<1, 64, 0, stream>>>(trans, out, ws, OBEST_OFF, OMAPS_OFF, OE_OFF, 0);
    bt_emit<<<NSEG, 64, 0, stream>>>(ws, out, OBP_OFF, OBEST_OFF, OE_OFF);
  }
}

// Round 5
// 2107.175 us; speedup vs baseline: 2.5876x; 1.1198x over previous
//
#include <hip/hip_runtime.h>

#define SQ 65536
#define BSEG 256
#define NSEG (SQ / BSEG)
#define NEGV (-10000.0f)
#define PADV (-1.0e30f)

// ---- New (deferred-argmax, batched-trace) ws layout ----
// TRACE: [SQ/4][8 lanes][4 steps] f32  = SQ*32 B = 2 MB
// DUMP : 4 KB scratch for replica-lane stores (ring, L2-resident)
#define TRACE_OFF 0u
#define DUMP_OFF  ((unsigned)SQ * 32u)
#define BP_OFF    (DUMP_OFF + 4096u)
#define BEST_OFF  (BP_OFF + (unsigned)SQ * 8u)
#define MAPS_OFF  (BEST_OFF + 32u)
#define E_OFF     (MAPS_OFF + (unsigned)NSEG * 8u)
#define WS_NEEDED ((size_t)(E_OFF + NSEG + 64))

// ---- Old (fallback) ws layout ----
#define OBP_OFF   0u
#define OBEST_OFF ((unsigned)SQ * 8u)
#define OMAPS_OFF (OBEST_OFF + 32u)
#define OE_OFF    (OMAPS_OFF + (unsigned)NSEG * 8u)

__device__ __forceinline__ float rl(float v, int l) {
  return __int_as_float(__builtin_amdgcn_readlane(__float_as_int(v), l));
}

template <int K>
__device__ __forceinline__ float ror16(float v) {
  return __int_as_float(
      __builtin_amdgcn_update_dpp(0, __float_as_int(v), 0x120 + K, 0xF, 0xF, true));
}
template <int K>
__device__ __forceinline__ int ror16i(int v) {
  return __builtin_amdgcn_update_dpp(0, v, 0x120 + K, 0xF, 0xF, true);
}

// ================== forward: DPP distribution, deferred argmax, batched stores ==================
__global__ __launch_bounds__(64, 1)
void viterbi_fwd_dpp2(const float* __restrict__ feats, const float* __restrict__ trans,
                      unsigned char* __restrict__ ws) {
  const int lane = threadIdx.x & 63;
  const int r = lane & 7;
  const int row = r < 6 ? r : 5;  // lanes 6,7 (mod 8) replicate tag 5

  // Probe DPP row_ror direction (HW convention safe)
  int w = ror16i<1>(lane & 15);
  const int dir = (__builtin_amdgcn_readfirstlane(w) == 1) ? 1 : -1;

  // TT[k] pairs with the value arriving via ror16<k>: fv of tag (r + dir*k) & 7
  float TT[8];
#pragma unroll
  for (int k = 0; k < 8; ++k) {
    int p = (r + dir * k) & 7;
    TT[k] = (p < 6) ? trans[row * 6 + p] : PADV;
  }

  const float* fp = feats + row;
  float nfv = (row == 4) ? 0.0f : NEGV;  // init fv (START=4 is 0)

  // Store plumbing: lanes 0-7 write the real trace, lanes 8-63 a fixed dump slot.
  // All 64 addresses are UNIQUE within each store op (no coalescer splitting).
  unsigned voff = (lane < 8) ? (TRACE_OFF + (unsigned)lane * 16u)
                             : (DUMP_OFF + (unsigned)lane * 16u);
  const unsigned vstep = (lane < 8) ? 128u : 0u;

  float fq[16];
#pragma unroll
  for (int i = 0; i < 16; ++i) fq[i] = fp[i * 6];

  auto step = [&](float ft) {
    float d1 = ror16<1>(nfv), d2 = ror16<2>(nfv), d3 = ror16<3>(nfv), d4 = ror16<4>(nfv),
          d5 = ror16<5>(nfv), d6 = ror16<6>(nfv), d7 = ror16<7>(nfv);
    float s0 = nfv + TT[0], s1 = d1 + TT[1], s2 = d2 + TT[2], s3 = d3 + TT[3],
          s4 = d4 + TT[4], s5 = d5 + TT[5], s6 = d6 + TT[6], s7 = d7 + TT[7];
    float A = fmaxf(fmaxf(s0, s1), s2);   // v_max3
    float B = fmaxf(fmaxf(s3, s4), s5);   // v_max3
    float C = fmaxf(s6, s7);
    float M = fmaxf(fmaxf(A, B), C);      // max reassociation is exact
    nfv = M + ft;                         // reference add order: max + feat
  };

  for (int blk = 0; blk < SQ / 16 - 1; ++blk) {
    const int t = blk * 16;
#pragma unroll
    for (int b = 0; b < 4; ++b) {
      float b0, b1, b2, b3;
      step(fq[b * 4 + 0]); b0 = nfv; fq[b * 4 + 0] = fp[(t + b * 4 + 0 + 16) * 6];
      step(fq[b * 4 + 1]); b1 = nfv; fq[b * 4 + 1] = fp[(t + b * 4 + 1 + 16) * 6];
      step(fq[b * 4 + 2]); b2 = nfv; fq[b * 4 + 2] = fp[(t + b * 4 + 2 + 16) * 6];
      step(fq[b * 4 + 3]); b3 = nfv; fq[b * 4 + 3] = fp[(t + b * 4 + 3 + 16) * 6];
      *(float4*)(ws + voff) = make_float4(b0, b1, b2, b3);
      voff += vstep;
    }
  }
  {  // last 16 steps: no prefetch
#pragma unroll
    for (int b = 0; b < 4; ++b) {
      float b0, b1, b2, b3;
      step(fq[b * 4 + 0]); b0 = nfv;
      step(fq[b * 4 + 1]); b1 = nfv;
      step(fq[b * 4 + 2]); b2 = nfv;
      step(fq[b * 4 + 3]); b3 = nfv;
      *(float4*)(ws + voff) = make_float4(b0, b1, b2, b3);
      voff += vstep;
    }
  }
}

// ================== Parallel backpointer extraction (bit-exact recompute) ==================
__global__ __launch_bounds__(256)
void bp_kernel(const float* __restrict__ trans, unsigned char* __restrict__ ws) {
  const int t = blockIdx.x * 256 + threadIdx.x;
  float fv0, fv1, fv2, fv3, fv4, fv5;
  if (t == 0) {
    fv0 = NEGV; fv1 = NEGV; fv2 = NEGV; fv3 = NEGV; fv4 = 0.0f; fv5 = NEGV;
  } else {
    const int u = t - 1;                   // fv after step u
    const float* f = (const float*)(ws + TRACE_OFF) + (unsigned)(u >> 2) * 32u + (unsigned)(u & 3);
    fv0 = f[0]; fv1 = f[4]; fv2 = f[8]; fv3 = f[12]; fv4 = f[16]; fv5 = f[20];
  }
  unsigned long long acc = 0;
#pragma unroll
  for (int n = 0; n < 6; ++n) {
    float s0 = fv0 + trans[n * 6 + 0];
    float s1 = fv1 + trans[n * 6 + 1];
    float s2 = fv2 + trans[n * 6 + 2];
    float s3 = fv3 + trans[n * 6 + 3];
    float s4 = fv4 + trans[n * 6 + 4];
    float s5 = fv5 + trans[n * 6 + 5];
    float m = fmaxf(fmaxf(fmaxf(s0, s1), s2), fmaxf(fmaxf(s3, s4), s5));
    int idx = 5;
    idx = (s4 >= m) ? 4 : idx;
    idx = (s3 >= m) ? 3 : idx;
    idx = (s2 >= m) ? 2 : idx;
    idx = (s1 >= m) ? 1 : idx;
    idx = (s0 >= m) ? 0 : idx;  // numpy first-index tie rule
    acc |= (unsigned long long)idx << (8 * n);
  }
  ((unsigned long long*)(ws + BP_OFF))[t] = acc;
}

// ================== OLD forward (fallback if ws too small) ==================
__global__ __launch_bounds__(64, 1)
void viterbi_fwd_old(const float* __restrict__ feats, const float* __restrict__ trans,
                     float* __restrict__ out, unsigned char* __restrict__ ws) {
  const int lane = threadIdx.x;
  if (lane >= 6) return;
  const float T0 = trans[lane * 6 + 0], T1 = trans[lane * 6 + 1], T2 = trans[lane * 6 + 2],
              T3 = trans[lane * 6 + 3], T4 = trans[lane * 6 + 4], T5 = trans[lane * 6 + 5];
  float fv0 = NEGV, fv1 = NEGV, fv2 = NEGV, fv3 = NEGV, fv4 = 0.0f, fv5 = NEGV;
  unsigned char* bpb = ws + OBP_OFF + lane;
  const float* fp = feats + lane;
  float fq[16];
#pragma unroll
  for (int i = 0; i < 16; ++i) fq[i] = fp[i * 6];
  auto step = [&](float ft, int tt) {
    float sc0 = fv0 + T0, sc1 = fv1 + T1, sc2 = fv2 + T2;
    float sc3 = fv3 + T3, sc4 = fv4 + T4, sc5 = fv5 + T5;
    float m = fmaxf(fmaxf(fmaxf(sc0, sc1), sc2), fmaxf(fmaxf(sc3, sc4), sc5));
    int idx = 5;
    idx = (sc4 >= m) ? 4 : idx;
    idx = (sc3 >= m) ? 3 : idx;
    idx = (sc2 >= m) ? 2 : idx;
    idx = (sc1 >= m) ? 1 : idx;
    idx = (sc0 >= m) ? 0 : idx;
    bpb[(unsigned)tt * 8u] = (unsigned char)idx;
    float nfv = m + ft;
    fv0 = rl(nfv, 0); fv1 = rl(nfv, 1); fv2 = rl(nfv, 2);
    fv3 = rl(nfv, 3); fv4 = rl(nfv, 4); fv5 = rl(nfv, 5);
  };
  for (int blk = 0; blk < SQ / 16 - 1; ++blk) {
    const int t = blk * 16;
#pragma unroll
    for (int i = 0; i < 16; ++i) { step(fq[i], t + i); fq[i] = fp[(t + i + 16) * 6]; }
  }
  { const int t = SQ - 16;
#pragma unroll
    for (int i = 0; i < 16; ++i) step(fq[i], t + i); }
  const float q0 = trans[30], q1 = trans[31], q2 = trans[32],
              q3 = trans[33], q4 = trans[34], q5 = trans[35];
  float tv0 = fv0 + q0, tv1 = fv1 + q1, tv2 = fv2 + q2;
  float tv3 = fv3 + q3, tv4 = fv4 + q4, tv5 = fv5 + q5;
  float bm = tv0; int bi = 0;
  if (tv1 > bm) { bm = tv1; bi = 1; }
  if (tv2 > bm) { bm = tv2; bi = 2; }
  if (tv3 > bm) { bm = tv3; bi = 3; }
  if (tv4 > bm) { bm = tv4; bi = 4; }
  if (tv5 > bm) { bm = tv5; bi = 5; }
  if (lane == 0) { out[0] = bm; *(unsigned*)(ws + OBEST_OFF) = (unsigned)bi; }
}

// ================== Backtrack phases (offsets passed as args) ==================
__global__ __launch_bounds__(64, 1)
void bt_maps(unsigned char* __restrict__ ws, unsigned bp_off, unsigned maps_off) {
  const int s = blockIdx.x;
  const int lane = threadIdx.x;
  int x = lane < 6 ? lane : 5;
  const unsigned long long* g = (const unsigned long long*)(ws + bp_off);
  const int lo = s * BSEG + 1;
  const int hi = (s == NSEG - 1) ? (SQ - 1) : (s + 1) * BSEG;
#pragma unroll 8
  for (int j = hi; j >= lo; --j) {
    unsigned long long w = g[j];
    x = (int)((w >> (x * 8)) & 7ull);
  }
  if (lane < 6) ws[maps_off + (unsigned)s * 8u + (unsigned)lane] = (unsigned char)x;
}

// do_terminal!=0: compute terminal score/best from fv trace (new layout) and write out[0].
__global__ __launch_bounds__(64, 1)
void bt_chain(const float* __restrict__ trans, float* __restrict__ out,
              unsigned char* __restrict__ ws, unsigned best_off, unsigned maps_off,
              unsigned e_off, int do_terminal) {
  __shared__ unsigned char ml[NSEG * 8];
  const unsigned* src = (const unsigned*)(ws + maps_off);
  unsigned* dstw = (unsigned*)ml;
  for (int i = threadIdx.x; i < NSEG * 2; i += 64) dstw[i] = src[i];
  __syncthreads();
  if (threadIdx.x == 0) {
    if (do_terminal) {
      const int u = SQ - 1;
      const float* f = (const float*)(ws + TRACE_OFF) + (unsigned)(u >> 2) * 32u + (unsigned)(u & 3);
      float bm = f[0] + trans[30]; int bi = 0;
      float tv;
      tv = f[4]  + trans[31]; if (tv > bm) { bm = tv; bi = 1; }
      tv = f[8]  + trans[32]; if (tv > bm) { bm = tv; bi = 2; }
      tv = f[12] + trans[33]; if (tv > bm) { bm = tv; bi = 3; }
      tv = f[16] + trans[34]; if (tv > bm) { bm = tv; bi = 4; }
      tv = f[20] + trans[35]; if (tv > bm) { bm = tv; bi = 5; }
      out[0] = bm;
      *(unsigned*)(ws + best_off) = (unsigned)bi;
    }
    int x = (int)*(const unsigned*)(ws + best_off);
    for (int s = NSEG - 1; s >= 1; --s) {
      x = ml[s * 8 + x];
      ws[e_off + (unsigned)s] = (unsigned char)x;
    }
  }
}

__global__ __launch_bounds__(64, 1)
void bt_emit(const unsigned char* __restrict__ ws, float* __restrict__ out,
             unsigned bp_off, unsigned best_off, unsigned e_off) {
  const int s = blockIdx.x;
  if (threadIdx.x != 0) return;
  const unsigned long long* g = (const unsigned long long*)(ws + bp_off);
  int x, hi;
  const int lo = s * BSEG + 1;
  if (s == NSEG - 1) {
    x = (int)*(const unsigned*)(ws + best_off);
    out[1 + (SQ - 1)] = (float)x;
    hi = SQ - 1;
  } else {
    x = ws[e_off + (unsigned)(s + 1)];
    hi = (s + 1) * BSEG;
  }
#pragma unroll 8
  for (int j = hi; j >= lo; --j) {
    unsigned long long w = g[j];
    x = (int)((w >> (x * 8)) & 7ull);
    out[j] = (float)x;
  }
}

extern "C" void kernel_launch(void* const* d_in, const int* in_sizes, int n_in,
                              void* d_out, int out_size, void* d_ws, size_t ws_size,
                              hipStream_t stream) {
  const float* feats = (const float*)d_in[0];
  const float* trans = (const float*)d_in[1];
  float* out = (float*)d_out;
  unsigned char* ws = (unsigned char*)d_ws;

  if (ws_size >= WS_NEEDED) {
    viterbi_fwd_dpp2<<<1, 64, 0, stream>>>(feats, trans, ws);
    bp_kernel<<<NSEG, 256, 0, stream>>>(trans, ws);
    bt_maps<<<NSEG, 64, 0, stream>>>(ws, BP_OFF, MAPS_OFF);
    bt_chain<<<1, 64, 0, stream>>>(trans, out, ws, BEST_OFF, MAPS_OFF, E_OFF, 1);
    bt_emit<<<NSEG, 64, 0, stream>>>(ws, out, BP_OFF, BEST_OFF, E_OFF);
  } else {
    viterbi_fwd_old<<<1, 64, 0, stream>>>(feats, trans, out, ws);
    bt_maps<<<NSEG, 64, 0, stream>>>(ws, OBP_OFF, OMAPS_OFF);
    bt_chain<<<1, 64, 0, stream>>>(trans, out, ws, OBEST_OFF, OMAPS_OFF, OE_OFF, 0);
    bt_emit<<<NSEG, 64, 0, stream>>>(ws, out, OBP_OFF, OBEST_OFF, OE_OFF);
  }
}